// Round 3
// baseline (363.743 us; speedup 1.0000x reference)
//
#include <hip/hip_runtime.h>

// MemoryBank contrastive loss, steady state.
// B=1024, D=128, C=50, K=4096, N = C*K = 204800. TEMP=0.3.
// loss = (1/B) * sum_b w_b * ( ln(sum_{c,k} exp(dot(feat_b,mem_ck)/T)) - dot(feat_b,mem_{lab,0})/T )
//
// SCALE = log2(e)/T folded into normalized features (pre-bf16): MFMA acc t
// feeds exp2 directly. S_b = sum 2^t; loss_b = ln2*(log2 S_b - t_pos).
//
// R3: latency-hiding restructure. mf=4/nf=4 (4 MFMA per ds_read_b128),
// double-buffered LDS with ONE barrier per tile, global prefetch issued a full
// compute phase (~1500 cyc) ahead of use, 4-wave blocks (barrier couples only
// 4 waves), 3200 blocks for 6+ scheduling rounds. L3 dedups the 4x m-re-read.

#define TILE_N 64
#define NITER 4            // tiles per block; 204800/64/4 = 800 x-chunks
#define LN2f 0.6931471805599453f
#define SCALEf 4.808983469629878f   // log2(e)/0.3

typedef __attribute__((ext_vector_type(8))) short bf16x8;
typedef __attribute__((ext_vector_type(4))) float f32x4;

__device__ __forceinline__ unsigned short f2bf(float x) {
    union { float f; unsigned int u; } c; c.f = x;
    unsigned int u = c.u;
    u = (u + 0x7fffu + ((u >> 16) & 1u)) >> 16;   // RNE (features only)
    return (unsigned short)u;
}
__device__ __forceinline__ float bf2f(unsigned short h) {
    union { unsigned int u; float f; } c; c.u = ((unsigned int)h) << 16;
    return c.f;
}
// two fp32 -> two bf16 (truncation) in one v_perm_b32
__device__ __forceinline__ unsigned int pack_bf2(float lo, float hi) {
    union { float f; unsigned int u; } a, b; a.f = lo; b.f = hi;
    return __builtin_amdgcn_perm(b.u, a.u, 0x07060302u);
}

// ---- Kernel 1: normalize+scale features -> bf16; zero S and out -------------
__global__ void normalize_feat(const float* __restrict__ f,
                               unsigned short* __restrict__ featb,
                               float* __restrict__ S,
                               float* __restrict__ out) {
    const int b = blockIdx.x;          // 1024 blocks
    const int t = threadIdx.x;         // 128 threads (2 waves)
    if (t == 0) S[b] = 0.0f;
    if (b == 0 && t == 1) *out = 0.0f;
    float v = f[b * 128 + t];
    float ss = v * v;
    #pragma unroll
    for (int m = 1; m < 64; m <<= 1) ss += __shfl_xor(ss, m, 64);
    __shared__ float wsum[2];
    if ((t & 63) == 0) wsum[t >> 6] = ss;
    __syncthreads();
    float tot = wsum[0] + wsum[1];
    float inv = SCALEf / fmaxf(sqrtf(tot), 1e-12f);
    featb[b * 128 + t] = f2bf(v * inv);
}

// ---- Kernel 2: fused GEMM + exp2-sum ----------------------------------------
// Block: 256 threads = 4 waves, m-tile 256 (wave owns 64 rows, mf=4), n-tile 64.
// K=128 complete. A-frags in registers for all tiles. B: fp32 global -> regs ->
// bf16(perm) -> LDS (double-buffered, padded stride 136).
__global__ __launch_bounds__(256, 2) void gemm_lse(
        const unsigned short* __restrict__ featb,  // [1024][128] bf16 (scaled)
        const float* __restrict__ mem,             // [204800][128] fp32
        float* __restrict__ S)                     // [1024] exp2-sums
{
    __shared__ unsigned short ldsb[2][TILE_N * 136];  // 2 x 17408 B

    const int tid  = threadIdx.x;
    const int wave = tid >> 6;        // 0..3
    const int lane = tid & 63;
    const int col  = lane & 15;
    const int quad = lane >> 4;

    const int m_wave = blockIdx.y * 256 + wave * 64;

    // A fragments: A[m=col][k=quad*8+j], 4 m-frags x 4 k-steps (64 VGPR)
    bf16x8 afrag[4][4];
    #pragma unroll
    for (int mf = 0; mf < 4; ++mf)
        #pragma unroll
        for (int ks = 0; ks < 4; ++ks)
            afrag[mf][ks] = *(const bf16x8*)&featb[(size_t)(m_wave + mf * 16 + col) * 128
                                                   + ks * 32 + quad * 8];

    float s_part[16];
    #pragma unroll
    for (int i = 0; i < 16; ++i) s_part[i] = 0.0f;

    const int tile0 = blockIdx.x * NITER;

    // ---- prologue: tile0 -> buf0; issue tile1 loads ----
    float4 pf[8];
    {
        const float4* s0 = (const float4*)(mem + (size_t)tile0 * TILE_N * 128);
        #pragma unroll
        for (int i = 0; i < 8; ++i) pf[i] = s0[i * 256 + tid];
        #pragma unroll
        for (int i = 0; i < 8; ++i) {
            int g = i * 256 + tid;
            uint2 p;
            p.x = pack_bf2(pf[i].x, pf[i].y);
            p.y = pack_bf2(pf[i].z, pf[i].w);
            *(uint2*)&ldsb[0][(g >> 5) * 136 + (g & 31) * 4] = p;
        }
        const float4* s1 = (const float4*)(mem + (size_t)(tile0 + 1) * TILE_N * 128);
        #pragma unroll
        for (int i = 0; i < 8; ++i) pf[i] = s1[i * 256 + tid];
    }
    __syncthreads();

    for (int t = 0; t < NITER; ++t) {
        const unsigned short* buf = ldsb[t & 1];

        f32x4 acc[4][4];
        #pragma unroll
        for (int mf = 0; mf < 4; ++mf)
            #pragma unroll
            for (int nf = 0; nf < 4; ++nf)
                acc[mf][nf] = (f32x4)(0.0f);

        #pragma unroll
        for (int ks = 0; ks < 4; ++ks) {
            bf16x8 bfrag[4];   // B^T[n=nf*16+col][k=ks*32+quad*8+j]
            #pragma unroll
            for (int nf = 0; nf < 4; ++nf)
                bfrag[nf] = *(const bf16x8*)&buf[(nf * 16 + col) * 136 + ks * 32 + quad * 8];
            #pragma unroll
            for (int mf = 0; mf < 4; ++mf)
                #pragma unroll
                for (int nf = 0; nf < 4; ++nf)
                    acc[mf][nf] = __builtin_amdgcn_mfma_f32_16x16x32_bf16(
                        afrag[mf][ks], bfrag[nf], acc[mf][nf], 0, 0, 0);
        }

        // epilogue: s_part[mf*4+r] += 2^acc (row = quad*4+r within m-frag)
        #pragma unroll
        for (int mf = 0; mf < 4; ++mf)
            #pragma unroll
            for (int nf = 0; nf < 4; ++nf)
                #pragma unroll
                for (int r = 0; r < 4; ++r)
                    s_part[mf * 4 + r] += __builtin_amdgcn_exp2f(acc[mf][nf][r]);

        if (t + 1 < NITER) {
            // write tile t+1 (loads issued one full compute phase ago)
            unsigned short* wbuf = ldsb[(t + 1) & 1];
            #pragma unroll
            for (int i = 0; i < 8; ++i) {
                int g = i * 256 + tid;
                uint2 p;
                p.x = pack_bf2(pf[i].x, pf[i].y);
                p.y = pack_bf2(pf[i].z, pf[i].w);
                *(uint2*)&wbuf[(g >> 5) * 136 + (g & 31) * 4] = p;
            }
            // issue loads for tile t+2 (land during compute of t+1)
            if (t + 2 < NITER) {
                const float4* sn = (const float4*)(mem + (size_t)(tile0 + t + 2) * TILE_N * 128);
                #pragma unroll
                for (int i = 0; i < 8; ++i) pf[i] = sn[i * 256 + tid];
            }
            __syncthreads();
        }
    }

    // reduce across the 16 col-lanes sharing the same quad
    #pragma unroll
    for (int d = 1; d < 16; d <<= 1)
        #pragma unroll
        for (int i = 0; i < 16; ++i)
            s_part[i] += __shfl_xor(s_part[i], d, 64);

    if (col == 0) {
        #pragma unroll
        for (int i = 0; i < 16; ++i) {
            int row = m_wave + (i >> 2) * 16 + quad * 4 + (i & 3);
            atomicAdd(&S[row], s_part[i]);
        }
    }
}

// ---- Kernel 3: pos logit + weighted mean ------------------------------------
__global__ void finalize_k(const unsigned short* __restrict__ featb,
                           const float* __restrict__ mem,
                           const int* __restrict__ labels,
                           const float* __restrict__ S,
                           float* __restrict__ out) {
    const int wave = threadIdx.x >> 6;
    const int lane = threadIdx.x & 63;
    const int b = blockIdx.x * 4 + wave;          // 256 blocks x 4 waves = 1024
    const int lab = labels[b];
    const float* mrow = mem + (size_t)lab * (4096 * 128);   // memory[lab][0][:]
    float fa = bf2f(featb[b * 128 + lane]);
    float fc = bf2f(featb[b * 128 + lane + 64]);
    float p = fa * mrow[lane] + fc * mrow[lane + 64];       // t_pos partial
    #pragma unroll
    for (int m = 1; m < 64; m <<= 1) p += __shfl_xor(p, m, 64);
    if (lane == 0) {
        float w = (lab < 2) ? 1.3f : 1.0f;
        float v = w * LN2f * (log2f(S[b]) - p) * (1.0f / 1024.0f);
        atomicAdd(out, v);
    }
}

extern "C" void kernel_launch(void* const* d_in, const int* in_sizes, int n_in,
                              void* d_out, int out_size, void* d_ws, size_t ws_size,
                              hipStream_t stream) {
    const float* features = (const float*)d_in[0];
    const int*   labels   = (const int*)d_in[1];
    const float* memory   = (const float*)d_in[2];
    float* out = (float*)d_out;

    unsigned short* featb = (unsigned short*)d_ws;               // 256 KiB
    float* S = (float*)((char*)d_ws + 1024 * 128 * 2);           // 1024 floats

    normalize_feat<<<1024, 128, 0, stream>>>(features, featb, S, out);
    gemm_lse<<<dim3(800, 4), 256, 0, stream>>>(featb, memory, S);
    finalize_k<<<256, 256, 0, stream>>>(featb, memory, labels, S, out);
}

// Round 4
// 312.238 us; speedup vs baseline: 1.1650x; 1.1650x over previous
//
#include <hip/hip_runtime.h>

// MemoryBank contrastive loss, steady state.
// B=1024, D=128, C=50, K=4096, N = C*K = 204800. TEMP=0.3.
// loss = (1/B) * sum_b w_b * ( ln(sum exp(dot/T)) - dot_pos/T )
// SCALE = log2(e)/T folded into normalized bf16 features: MFMA acc feeds exp2.
//
// R4: pipeline restructure.
//  - 512-thr blocks (8 waves), wave owns 32m x 64n; nf-outer + exp2 folded ->
//    live acc = 8 VGPR; total ~116 VGPR -> 4 waves/SIMD, 2 blocks/CU exact.
//  - grid (128,4), NITER=25, STRIDED tiles (tile = x + 128*t): all blocks sweep
//    the same 4 MB slice simultaneously -> m-replica reads dedup in L2/L3.
//  - depth-2 register prefetch (pfA/pfB), loads issued at TOP of compute phase
//    (~5k cyc before the barrier's vmcnt(0) drain) -> drain is free.

#define TILE_N 64
#define XCHUNK 128
#define NITER 25           // 128 * 25 = 3200 tiles = 204800 rows
#define LN2f 0.6931471805599453f
#define SCALEf 4.808983469629878f   // log2(e)/0.3

typedef __attribute__((ext_vector_type(8))) short bf16x8;
typedef __attribute__((ext_vector_type(4))) float f32x4;

__device__ __forceinline__ unsigned short f2bf(float x) {
    union { float f; unsigned int u; } c; c.f = x;
    unsigned int u = c.u;
    u = (u + 0x7fffu + ((u >> 16) & 1u)) >> 16;   // RNE (features only)
    return (unsigned short)u;
}
__device__ __forceinline__ float bf2f(unsigned short h) {
    union { unsigned int u; float f; } c; c.u = ((unsigned int)h) << 16;
    return c.f;
}
// two fp32 -> two bf16 (truncation) in one v_perm_b32
__device__ __forceinline__ unsigned int pack_bf2(float lo, float hi) {
    union { float f; unsigned int u; } a, b; a.f = lo; b.f = hi;
    return __builtin_amdgcn_perm(b.u, a.u, 0x07060302u);
}

// ---- Kernel 1: normalize+scale features -> bf16; zero S and out -------------
__global__ void normalize_feat(const float* __restrict__ f,
                               unsigned short* __restrict__ featb,
                               float* __restrict__ S,
                               float* __restrict__ out) {
    const int b = blockIdx.x;          // 1024 blocks
    const int t = threadIdx.x;         // 128 threads
    if (t == 0) S[b] = 0.0f;
    if (b == 0 && t == 1) *out = 0.0f;
    float v = f[b * 128 + t];
    float ss = v * v;
    #pragma unroll
    for (int m = 1; m < 64; m <<= 1) ss += __shfl_xor(ss, m, 64);
    __shared__ float wsum[2];
    if ((t & 63) == 0) wsum[t >> 6] = ss;
    __syncthreads();
    float tot = wsum[0] + wsum[1];
    float inv = SCALEf / fmaxf(sqrtf(tot), 1e-12f);
    featb[b * 128 + t] = f2bf(v * inv);
}

// ---- Kernel 2: fused GEMM + exp2-sum ----------------------------------------
__global__ __launch_bounds__(512, 4) void gemm_lse(
        const unsigned short* __restrict__ featb,  // [1024][128] bf16 (scaled)
        const float* __restrict__ mem,             // [204800][128] fp32
        float* __restrict__ S)                     // [1024] exp2-sums
{
    __shared__ unsigned short ldsb[2][TILE_N * 136];  // padded stride 136 shorts

    const int tid  = threadIdx.x;
    const int wave = tid >> 6;        // 0..7
    const int lane = tid & 63;
    const int col  = lane & 15;
    const int quad = lane >> 4;

    const int m_wave = blockIdx.y * 256 + wave * 32;
    const int xc = blockIdx.x;        // 0..127

    // A fragments: A[m=col][k=quad*8+j], mf=2 x ks=4 (32 VGPR)
    bf16x8 afrag[2][4];
    #pragma unroll
    for (int mf = 0; mf < 2; ++mf)
        #pragma unroll
        for (int ks = 0; ks < 4; ++ks)
            afrag[mf][ks] = *(const bf16x8*)&featb[(size_t)(m_wave + mf * 16 + col) * 128
                                                   + ks * 32 + quad * 8];

    float s_part[8];
    #pragma unroll
    for (int i = 0; i < 8; ++i) s_part[i] = 0.0f;

    // staging helpers: tile = xc + 128*t; per-thread 4 float4 of the 64x128 tile
    const int g_n[4]  = { (0*512 + tid) >> 5, (1*512 + tid) >> 5,
                          (2*512 + tid) >> 5, (3*512 + tid) >> 5 };
    const int g_k4[4] = { ((0*512 + tid) & 31) * 4, ((1*512 + tid) & 31) * 4,
                          ((2*512 + tid) & 31) * 4, ((3*512 + tid) & 31) * 4 };

    float4 pfA[4], pfB[4];

    #define LOAD_PF(pf, t_) {                                                   \
        const float4* s_ = (const float4*)(mem + (size_t)(xc + XCHUNK * (t_)) * (TILE_N * 128)); \
        _Pragma("unroll")                                                       \
        for (int i = 0; i < 4; ++i) (pf)[i] = s_[i * 512 + tid]; }

    #define WRITE_PF(pf, bi) {                                                  \
        _Pragma("unroll")                                                       \
        for (int i = 0; i < 4; ++i) {                                           \
            uint2 p_;                                                           \
            p_.x = pack_bf2((pf)[i].x, (pf)[i].y);                              \
            p_.y = pack_bf2((pf)[i].z, (pf)[i].w);                              \
            *(uint2*)&ldsb[bi][g_n[i] * 136 + g_k4[i]] = p_; } }

    #define COMPUTE(bi) {                                                       \
        _Pragma("unroll")                                                       \
        for (int nf = 0; nf < 4; ++nf) {                                        \
            bf16x8 bfrag[4];                                                    \
            _Pragma("unroll")                                                   \
            for (int ks = 0; ks < 4; ++ks)                                      \
                bfrag[ks] = *(const bf16x8*)&ldsb[bi][(nf * 16 + col) * 136 + ks * 32 + quad * 8]; \
            f32x4 acc0 = (f32x4)(0.0f), acc1 = (f32x4)(0.0f);                   \
            _Pragma("unroll")                                                   \
            for (int ks = 0; ks < 4; ++ks) {                                    \
                acc0 = __builtin_amdgcn_mfma_f32_16x16x32_bf16(afrag[0][ks], bfrag[ks], acc0, 0, 0, 0); \
                acc1 = __builtin_amdgcn_mfma_f32_16x16x32_bf16(afrag[1][ks], bfrag[ks], acc1, 0, 0, 0); \
            }                                                                   \
            _Pragma("unroll")                                                   \
            for (int r = 0; r < 4; ++r) {                                       \
                s_part[r]     += __builtin_amdgcn_exp2f(acc0[r]);               \
                s_part[4 + r] += __builtin_amdgcn_exp2f(acc1[r]);               \
            } } }

    // ---- prologue: tile0 -> buf0 (staged now), tile1 -> pfB (in flight) ----
    LOAD_PF(pfA, 0)
    LOAD_PF(pfB, 1)
    WRITE_PF(pfA, 0)        // waits only pfA's loads; pfB stays in flight
    __syncthreads();

    // ---- steady state, unrolled x2 (t even: held=pfB; t odd: held=pfA) ----
    for (int tp = 0; tp < 12; ++tp) {
        const int t0 = 2 * tp;
        // tile t0 (even): issue loads for t0+2 early, compute, publish t0+1
        if (t0 + 2 < NITER) LOAD_PF(pfA, t0 + 2)
        COMPUTE(0)
        WRITE_PF(pfB, 1)                 // tile t0+1 (always < 25 here)
        __syncthreads();
        // tile t0+1 (odd)
        if (t0 + 3 < NITER) LOAD_PF(pfB, t0 + 3)
        COMPUTE(1)
        if (t0 + 2 < NITER) WRITE_PF(pfA, 0)
        __syncthreads();
    }
    // tail: tile 24 sits in buf0
    COMPUTE(0)

    // reduce across the 16 col-lanes sharing the same quad
    #pragma unroll
    for (int d = 1; d < 16; d <<= 1)
        #pragma unroll
        for (int i = 0; i < 8; ++i)
            s_part[i] += __shfl_xor(s_part[i], d, 64);

    if (col == 0) {
        #pragma unroll
        for (int i = 0; i < 8; ++i) {
            int row = m_wave + (i >> 2) * 16 + quad * 4 + (i & 3);
            atomicAdd(&S[row], s_part[i]);
        }
    }
    #undef LOAD_PF
    #undef WRITE_PF
    #undef COMPUTE
}

// ---- Kernel 3: pos logit + weighted mean ------------------------------------
__global__ void finalize_k(const unsigned short* __restrict__ featb,
                           const float* __restrict__ mem,
                           const int* __restrict__ labels,
                           const float* __restrict__ S,
                           float* __restrict__ out) {
    const int wave = threadIdx.x >> 6;
    const int lane = threadIdx.x & 63;
    const int b = blockIdx.x * 4 + wave;          // 256 blocks x 4 waves = 1024
    const int lab = labels[b];
    const float* mrow = mem + (size_t)lab * (4096 * 128);   // memory[lab][0][:]
    float fa = bf2f(featb[b * 128 + lane]);
    float fc = bf2f(featb[b * 128 + lane + 64]);
    float p = fa * mrow[lane] + fc * mrow[lane + 64];       // t_pos (log2 domain)
    #pragma unroll
    for (int m = 1; m < 64; m <<= 1) p += __shfl_xor(p, m, 64);
    if (lane == 0) {
        float w = (lab < 2) ? 1.3f : 1.0f;
        float v = w * LN2f * (log2f(S[b]) - p) * (1.0f / 1024.0f);
        atomicAdd(out, v);
    }
}

extern "C" void kernel_launch(void* const* d_in, const int* in_sizes, int n_in,
                              void* d_out, int out_size, void* d_ws, size_t ws_size,
                              hipStream_t stream) {
    const float* features = (const float*)d_in[0];
    const int*   labels   = (const int*)d_in[1];
    const float* memory   = (const float*)d_in[2];
    float* out = (float*)d_out;

    unsigned short* featb = (unsigned short*)d_ws;               // 256 KiB
    float* S = (float*)((char*)d_ws + 1024 * 128 * 2);           // 1024 floats

    normalize_feat<<<1024, 128, 0, stream>>>(features, featb, S, out);
    gemm_lse<<<dim3(XCHUNK, 4), 512, 0, stream>>>(featb, memory, S);
    finalize_k<<<256, 256, 0, stream>>>(featb, memory, labels, S, out);
}

// Round 5
// 215.395 us; speedup vs baseline: 1.6887x; 1.4496x over previous
//
#include <hip/hip_runtime.h>

// MemoryBank contrastive loss, steady state.
// B=1024, D=128, C=50, K=4096, N = C*K = 204800. TEMP=0.3.
// loss = (1/B) * sum_b w_b * ( ln(sum exp(dot/T)) - dot_pos/T )
// SCALE = log2(e)/T folded into normalized bf16 features: MFMA acc feeds exp2.
//
// R5: kill the spill (R4: WRITE_SIZE 201 MB of scratch). Stage fp32 tiles
// straight to LDS with global_load_lds width=16 (no staging VGPRs -> nothing
// to spill; loads tracked by vmcnt, drained by the pre-barrier waitcnt).
// Per-lane GLOBAL addresses are free, only LDS dest is base+lane*16, so the
// bank swizzle is applied on the global side: granule q of row r -> LDS slot
// q^(r&7). Fragment reads then hit 8 lanes per 4-bank group = conflict-free
// minimum for ds_read_b128. fp32->bf16 conversion happens at fragment read
// (2x ds_read_b128 + 4 v_perm per frag). mf=4/nf=4: 16 MFMA per 8 ds_reads.
// Grid (128,4) = 512 blocks = exactly 2/CU; strided tiles for L3 dedup.

#define XCHUNK 128
#define NITER 25           // 128 * 25 = 3200 tiles of 64 rows = 204800
#define TILE_BYTES 32768   // 64 rows x 128 fp32
#define LN2f 0.6931471805599453f
#define SCALEf 4.808983469629878f   // log2(e)/0.3

typedef __attribute__((ext_vector_type(8))) short bf16x8;
typedef __attribute__((ext_vector_type(4))) float f32x4;
typedef unsigned int u32;

__device__ __forceinline__ unsigned short f2bf(float x) {
    union { float f; unsigned int u; } c; c.f = x;
    unsigned int u = c.u;
    u = (u + 0x7fffu + ((u >> 16) & 1u)) >> 16;   // RNE (features only)
    return (unsigned short)u;
}
__device__ __forceinline__ float bf2f(unsigned short h) {
    union { unsigned int u; float f; } c; c.u = ((unsigned int)h) << 16;
    return c.f;
}
// two fp32 -> two bf16 (truncation) in one v_perm_b32: [bf(lo) | bf(hi)<<16]
__device__ __forceinline__ unsigned int pack_bf2(float lo, float hi) {
    union { float f; unsigned int u; } a, b; a.f = lo; b.f = hi;
    return __builtin_amdgcn_perm(b.u, a.u, 0x07060302u);
}
// async DMA global -> LDS, 16 B per lane; gp is per-lane, lp wave-uniform
__device__ __forceinline__ void gl_lds16(const void* gp, void* lp) {
    __builtin_amdgcn_global_load_lds(
        (const __attribute__((address_space(1))) u32*)gp,
        (__attribute__((address_space(3))) u32*)lp, 16, 0, 0);
}

// ---- Kernel 1: normalize+scale features -> bf16; zero S and out -------------
__global__ void normalize_feat(const float* __restrict__ f,
                               unsigned short* __restrict__ featb,
                               float* __restrict__ S,
                               float* __restrict__ out) {
    const int b = blockIdx.x;          // 1024 blocks
    const int t = threadIdx.x;         // 128 threads
    if (t == 0) S[b] = 0.0f;
    if (b == 0 && t == 1) *out = 0.0f;
    float v = f[b * 128 + t];
    float ss = v * v;
    #pragma unroll
    for (int m = 1; m < 64; m <<= 1) ss += __shfl_xor(ss, m, 64);
    __shared__ float wsum[2];
    if ((t & 63) == 0) wsum[t >> 6] = ss;
    __syncthreads();
    float tot = wsum[0] + wsum[1];
    float inv = SCALEf / fmaxf(sqrtf(tot), 1e-12f);
    featb[b * 128 + t] = f2bf(v * inv);
}

// ---- Kernel 2: fused GEMM + exp2-sum ----------------------------------------
// 256 thr = 4 waves; wave owns 64 m-rows (mf=4), n-tile 64, K=128 complete.
__global__ __launch_bounds__(256, 2) void gemm_lse(
        const unsigned short* __restrict__ featb,  // [1024][128] bf16 (scaled)
        const float* __restrict__ mem,             // [204800][128] fp32
        float* __restrict__ S)                     // [1024] exp2-sums
{
    __shared__ float ldsb[2][64 * 128];            // 2 x 32 KB, swizzled granules

    const int tid  = threadIdx.x;
    const int wave = tid >> 6;        // 0..3
    const int lane = tid & 63;
    const int col  = lane & 15;
    const int quad = lane >> 4;
    const int c3   = col & 7;

    const int m_wave = blockIdx.y * 256 + wave * 64;
    const int xc = blockIdx.x;        // 0..127

    // A fragments: A[m=col][k=quad*8+j], mf=4 x ks=4 (64 VGPR)
    bf16x8 afrag[4][4];
    #pragma unroll
    for (int mf = 0; mf < 4; ++mf)
        #pragma unroll
        for (int ks = 0; ks < 4; ++ks)
            afrag[mf][ks] = *(const bf16x8*)&featb[(size_t)(m_wave + mf * 16 + col) * 128
                                                   + ks * 32 + quad * 8];

    float s_part[16];
    #pragma unroll
    for (int i = 0; i < 16; ++i) s_part[i] = 0.0f;

    // per-lane swizzled global byte offsets for the 8 DMA issues (tile-invariant)
    int goffb[8];
    #pragma unroll
    for (int i = 0; i < 8; ++i) {
        int s_lin = i * 256 + tid;      // LDS granule index 0..2047
        int row  = s_lin >> 5;          // 32 granules (16 B) per row
        int slot = s_lin & 31;
        int q    = slot ^ (row & 7);    // global granule living at this slot
        goffb[i] = row * 512 + q * 16;  // bytes within tile
    }

    #define STAGE(bi, t_) {                                                     \
        const char* gt = (const char*)mem + (size_t)(xc + XCHUNK * (t_)) * TILE_BYTES; \
        _Pragma("unroll")                                                       \
        for (int i = 0; i < 8; ++i)                                             \
            gl_lds16(gt + goffb[i],                                             \
                     (char*)&ldsb[bi][0] + (i * 4096 + wave * 1024)); }

    #define COMPUTE(bi) {                                                       \
        const float* buf = &ldsb[bi][0];                                        \
        _Pragma("unroll")                                                       \
        for (int nf = 0; nf < 4; ++nf) {                                        \
            const float* rbase = buf + (nf * 16 + col) * 128;                   \
            bf16x8 bfrag[4];                                                    \
            _Pragma("unroll")                                                   \
            for (int ks = 0; ks < 4; ++ks) {                                    \
                int s0 = (((ks * 8 + quad * 2 + 0) ^ c3) * 4);                  \
                int s1 = (((ks * 8 + quad * 2 + 1) ^ c3) * 4);                  \
                float4 f0 = *(const float4*)(rbase + s0);                       \
                float4 f1 = *(const float4*)(rbase + s1);                       \
                uint4 pk;                                                       \
                pk.x = pack_bf2(f0.x, f0.y); pk.y = pack_bf2(f0.z, f0.w);       \
                pk.z = pack_bf2(f1.x, f1.y); pk.w = pack_bf2(f1.z, f1.w);       \
                bfrag[ks] = *(bf16x8*)&pk;                                      \
            }                                                                   \
            f32x4 acc[4];                                                       \
            _Pragma("unroll")                                                   \
            for (int mf = 0; mf < 4; ++mf) acc[mf] = (f32x4)(0.0f);             \
            _Pragma("unroll")                                                   \
            for (int ks = 0; ks < 4; ++ks)                                      \
                _Pragma("unroll")                                               \
                for (int mf = 0; mf < 4; ++mf)                                  \
                    acc[mf] = __builtin_amdgcn_mfma_f32_16x16x32_bf16(          \
                        afrag[mf][ks], bfrag[ks], acc[mf], 0, 0, 0);            \
            _Pragma("unroll")                                                   \
            for (int mf = 0; mf < 4; ++mf)                                      \
                _Pragma("unroll")                                               \
                for (int r = 0; r < 4; ++r)                                     \
                    s_part[mf * 4 + r] += __builtin_amdgcn_exp2f(acc[mf][r]);   \
        } }

    // prologue: DMA tile 0 into buf0; barrier drains vmcnt
    STAGE(0, 0)
    __syncthreads();

    for (int t = 0; t < NITER; ++t) {
        if (t + 1 < NITER) STAGE((t + 1) & 1, t + 1)   // in flight during compute
        COMPUTE(t & 1)
        __syncthreads();   // drains next tile's DMA + protects buffer reuse
    }

    // reduce across the 16 col-lanes sharing the same quad
    #pragma unroll
    for (int d = 1; d < 16; d <<= 1)
        #pragma unroll
        for (int i = 0; i < 16; ++i)
            s_part[i] += __shfl_xor(s_part[i], d, 64);

    if (col == 0) {
        #pragma unroll
        for (int i = 0; i < 16; ++i) {
            int row = m_wave + (i >> 2) * 16 + quad * 4 + (i & 3);
            atomicAdd(&S[row], s_part[i]);
        }
    }
    #undef STAGE
    #undef COMPUTE
}

// ---- Kernel 3: pos logit + weighted mean ------------------------------------
__global__ void finalize_k(const unsigned short* __restrict__ featb,
                           const float* __restrict__ mem,
                           const int* __restrict__ labels,
                           const float* __restrict__ S,
                           float* __restrict__ out) {
    const int wave = threadIdx.x >> 6;
    const int lane = threadIdx.x & 63;
    const int b = blockIdx.x * 4 + wave;          // 256 blocks x 4 waves = 1024
    const int lab = labels[b];
    const float* mrow = mem + (size_t)lab * (4096 * 128);   // memory[lab][0][:]
    float fa = bf2f(featb[b * 128 + lane]);
    float fc = bf2f(featb[b * 128 + lane + 64]);
    float p = fa * mrow[lane] + fc * mrow[lane + 64];       // t_pos (log2 domain)
    #pragma unroll
    for (int m = 1; m < 64; m <<= 1) p += __shfl_xor(p, m, 64);
    if (lane == 0) {
        float w = (lab < 2) ? 1.3f : 1.0f;
        float v = w * LN2f * (log2f(S[b]) - p) * (1.0f / 1024.0f);
        atomicAdd(out, v);
    }
}

extern "C" void kernel_launch(void* const* d_in, const int* in_sizes, int n_in,
                              void* d_out, int out_size, void* d_ws, size_t ws_size,
                              hipStream_t stream) {
    const float* features = (const float*)d_in[0];
    const int*   labels   = (const int*)d_in[1];
    const float* memory   = (const float*)d_in[2];
    float* out = (float*)d_out;

    unsigned short* featb = (unsigned short*)d_ws;               // 256 KiB
    float* S = (float*)((char*)d_ws + 1024 * 128 * 2);           // 1024 floats

    normalize_feat<<<1024, 128, 0, stream>>>(features, featb, S, out);
    gemm_lse<<<dim3(XCHUNK, 4), 256, 0, stream>>>(featb, memory, S);
    finalize_k<<<256, 256, 0, stream>>>(featb, memory, labels, S, out);
}